// Round 4
// baseline (309.360 us; speedup 1.0000x reference)
//
#include <hip/hip_runtime.h>
#include <hip/hip_bf16.h>
#include <math.h>

// ParallelMLayer: x_seq, v_seq = scan over A=sigmoid(F@WA.T+bA),
// dt=softplus(F@Wdt.T+bdt)*0.1*1.5^(d/128), B=(F@WB.T+bB)*dt
// v_t = A_t v_{t-1} + B_t ; x_t = x_{t-1} + dt_t * v_t
//
// R4: GEMM switched to m97 structure (global_load_lds width-16, linear LDS,
// 2-barrier K-loop); scans vectorized to float4 with NCH=128; weight cvts fused.

#define BDIM 4
#define LSEQ 4096
#define DDIM 1024
#define MROWS (BDIM*LSEQ)   // 16384
#define NCH 128             // scan chunks per sequence
#define CLEN (LSEQ/NCH)     // 32
#define N4W (DDIM*DDIM/4)   // 262144 (2^18)

typedef __attribute__((ext_vector_type(8))) unsigned short u16x8;
typedef __attribute__((ext_vector_type(8))) short s16x8;
typedef __attribute__((ext_vector_type(4))) float f32x4;

__device__ inline ushort f2bf(float f) {
    unsigned u = __builtin_bit_cast(unsigned, f);
    unsigned r = (u + 0x7fffu + ((u >> 16) & 1u)) >> 16;
    return (ushort)r;
}

__device__ inline void gld_lds16(const ushort* g, ushort* l) {
    __builtin_amdgcn_global_load_lds(
        (const __attribute__((address_space(1))) void*)g,
        (__attribute__((address_space(3))) void*)l, 16, 0, 0);
}

// ---- f32 -> bf16 conversion, 4 elems/thread ----
__global__ void cvt4(const float* __restrict__ src, ushort* __restrict__ dst, int n4) {
    int i = blockIdx.x * 256 + threadIdx.x;
    if (i >= n4) return;
    float4 v = reinterpret_cast<const float4*>(src)[i];
    ushort4 o;
    o.x = f2bf(v.x); o.y = f2bf(v.y); o.z = f2bf(v.z); o.w = f2bf(v.w);
    reinterpret_cast<ushort4*>(dst)[i] = o;
}

// ---- three equal-size weight matrices -> one concatenated bf16 buffer ----
__global__ void cvt4_w3(const float* __restrict__ s0, const float* __restrict__ s1,
                        const float* __restrict__ s2, ushort* __restrict__ dst) {
    int i = blockIdx.x * 256 + threadIdx.x;      // 0 .. 3*N4W-1
    int w = i >> 18;                             // N4W = 2^18
    int j = i & (N4W - 1);
    const float* s = (w == 0) ? s0 : (w == 1) ? s1 : s2;
    float4 v = reinterpret_cast<const float4*>(s)[j];
    ushort4 o;
    o.x = f2bf(v.x); o.y = f2bf(v.y); o.z = f2bf(v.z); o.w = f2bf(v.w);
    reinterpret_cast<ushort4*>(dst)[i] = o;
}

// ---- fused GEMM: C[i][j] = sum_k F[i][k] * Wcat[j][k] ----
// m97 structure: 128x128 tile, BK=32, global_load_lds(16B) -> linear LDS [128][32].
__global__ __launch_bounds__(256) void gemm_fused(
    const ushort* __restrict__ F, const ushort* __restrict__ Wc,
    const float* __restrict__ biasA, const float* __restrict__ biasB,
    const float* __restrict__ biasDt,
    float* __restrict__ outA, float* __restrict__ outPre, float* __restrict__ outDt)
{
    __shared__ ushort As[128 * 32];
    __shared__ ushort Bs[128 * 32];
    const int t = threadIdx.x;
    const int bi = blockIdx.x;   // 0..127 M tiles
    const int bj = blockIdx.y;   // 0..23  N tiles
    const int lane = t & 63, wid = t >> 6;
    const int wm = wid >> 1, wn = wid & 1;   // 2x2 waves, each 64x64 out
    const int lr = lane & 15, lg = lane >> 4;

    const size_t aBase = (size_t)bi * 128;
    const size_t bBase = (size_t)bj * 128;
    // staging: thread t covers tile row (t>>2) [+64 for 2nd issue], 16B chunk (t&3)
    const ushort* gA0 = F + (aBase + (t >> 2)) * DDIM + (t & 3) * 8;
    const ushort* gA1 = gA0 + (size_t)64 * DDIM;
    const ushort* gB0 = Wc + (bBase + (t >> 2)) * DDIM + (t & 3) * 8;
    const ushort* gB1 = gB0 + (size_t)64 * DDIM;
    // LDS dests: wave-uniform base; HW adds lane*16 bytes (linear layout)
    ushort* lA0 = As + wid * 512;
    ushort* lA1 = As + 2048 + wid * 512;
    ushort* lB0 = Bs + wid * 512;
    ushort* lB1 = Bs + 2048 + wid * 512;

    f32x4 acc[4][4] = {};

    for (int k0 = 0; k0 < DDIM; k0 += 32) {
        __syncthreads();                 // prev iter's ds_reads done before overwrite
        gld_lds16(gA0 + k0, lA0);
        gld_lds16(gA1 + k0, lA1);
        gld_lds16(gB0 + k0, lB0);
        gld_lds16(gB1 + k0, lB1);
        __syncthreads();                 // drains vmcnt before barrier
        s16x8 af[4], bf[4];
#pragma unroll
        for (int m = 0; m < 4; m++)
            af[m] = *reinterpret_cast<const s16x8*>(&As[(wm * 64 + m * 16 + lr) * 32 + lg * 8]);
#pragma unroll
        for (int n = 0; n < 4; n++)
            bf[n] = *reinterpret_cast<const s16x8*>(&Bs[(wn * 64 + n * 16 + lr) * 32 + lg * 8]);
#pragma unroll
        for (int m = 0; m < 4; m++)
#pragma unroll
            for (int n = 0; n < 4; n++)
                acc[m][n] = __builtin_amdgcn_mfma_f32_16x16x32_bf16(af[m], bf[n], acc[m][n], 0, 0, 0);
    }

    // epilogue: C/D layout col=lane&15, row=(lane>>4)*4+reg
    const int mat = bj >> 3;                     // 0:A 1:B-pre 2:dt
    const int colBase = (bj & 7) * 128 + wn * 64;
    const size_t rowBase = (size_t)bi * 128 + wm * 64;

    if (mat == 0) {
#pragma unroll
        for (int n = 0; n < 4; n++) {
            const int d = colBase + n * 16 + lr;
            const float bb = biasA[d];
#pragma unroll
            for (int m = 0; m < 4; m++)
#pragma unroll
                for (int r = 0; r < 4; r++) {
                    const size_t row = rowBase + m * 16 + lg * 4 + r;
                    float s = acc[m][n][r] + bb;
                    outA[row * DDIM + d] = 1.0f / (1.0f + expf(-s));
                }
        }
    } else if (mat == 1) {
#pragma unroll
        for (int n = 0; n < 4; n++) {
            const int d = colBase + n * 16 + lr;
            const float bb = biasB[d];
#pragma unroll
            for (int m = 0; m < 4; m++)
#pragma unroll
                for (int r = 0; r < 4; r++) {
                    const size_t row = rowBase + m * 16 + lg * 4 + r;
                    outPre[row * DDIM + d] = acc[m][n][r] + bb;
                }
        }
    } else {
#pragma unroll
        for (int n = 0; n < 4; n++) {
            const int d = colBase + n * 16 + lr;
            const float bb = biasDt[d];
            const float scl = 0.1f * exp2f(0.58496250072f * (float)(d >> 7)); // 0.1*1.5^(d/128)
#pragma unroll
            for (int m = 0; m < 4; m++)
#pragma unroll
                for (int r = 0; r < 4; r++) {
                    const size_t row = rowBase + m * 16 + lg * 4 + r;
                    float s = acc[m][n][r] + bb;
                    float sp = fmaxf(s, 0.0f) + log1pf(expf(-fabsf(s)));
                    outDt[row * DDIM + d] = sp * scl;
                }
        }
    }
}

// ---- scan pass 1: per (b, chunk, d) composite map (a, c, bv, bx), float4 ----
__global__ void scan_pass1(const float* __restrict__ A, const float* __restrict__ PRE,
                           const float* __restrict__ DT, float4* __restrict__ summ)
{
    const int c = blockIdx.x & (NCH - 1);
    const int b = blockIdx.x >> 7;       // NCH = 128
    const int d4 = threadIdx.x;          // 0..255, covers d = 4*d4..+3
    const f32x4* A4   = (const f32x4*)A;
    const f32x4* PRE4 = (const f32x4*)PRE;
    const f32x4* DT4  = (const f32x4*)DT;
    size_t idx = ((size_t)b * LSEQ + (size_t)c * CLEN) * (DDIM / 4) + d4;
    f32x4 a = {1.f,1.f,1.f,1.f}, cc = {}, bv = {}, bx = {};
    for (int i = 0; i < CLEN; i++) {
        f32x4 Av = A4[idx], pv = PRE4[idx], dtv = DT4[idx];
#pragma unroll
        for (int j = 0; j < 4; j++) {
            a[j] *= Av[j];
            cc[j] = fmaf(dtv[j], a[j], cc[j]);
            bv[j] = fmaf(Av[j], bv[j], pv[j] * dtv[j]);
            bx[j] = fmaf(dtv[j], bv[j], bx[j]);
        }
        idx += DDIM / 4;
    }
    const size_t base = ((size_t)b * NCH + c) * DDIM + (size_t)d4 * 4;
#pragma unroll
    for (int j = 0; j < 4; j++)
        summ[base + j] = make_float4(a[j], cc[j], bv[j], bx[j]);
}

// ---- scan pass 2: serial over chunks per channel -> carry-in (v, x) ----
__global__ void scan_pass2(const float4* __restrict__ summ, float2* __restrict__ carry)
{
    const int idx = blockIdx.x * 256 + threadIdx.x;   // 4096 channels
    const int b = idx >> 10, d = idx & 1023;
    float v = 0.0f, x = 0.0f;
    for (int c = 0; c < NCH; c++) {
        const size_t o = ((size_t)b * NCH + c) * DDIM + d;
        carry[o] = make_float2(v, x);
        float4 s = summ[o];
        x = x + s.y * v + s.w;   // x' = x + c*v + bx (uses OLD v)
        v = s.x * v + s.z;       // v' = a*v + bv
    }
}

// ---- scan pass 3: finalize with carry; in-place pre->v_seq, dt->x_seq ----
__global__ void scan_pass3(const float* __restrict__ A, float* __restrict__ PREV,
                           float* __restrict__ DTX, const float2* __restrict__ carry)
{
    const int c = blockIdx.x & (NCH - 1);
    const int b = blockIdx.x >> 7;
    const int d4 = threadIdx.x;
    const f32x4* A4 = (const f32x4*)A;
    f32x4* PREV4 = (f32x4*)PREV;
    f32x4* DTX4  = (f32x4*)DTX;
    size_t idx = ((size_t)b * LSEQ + (size_t)c * CLEN) * (DDIM / 4) + d4;
    const size_t cbase = ((size_t)b * NCH + c) * DDIM + (size_t)d4 * 4;
    f32x4 v, x;
#pragma unroll
    for (int j = 0; j < 4; j++) {
        float2 cr = carry[cbase + j];
        v[j] = cr.x; x[j] = cr.y;
    }
    for (int i = 0; i < CLEN; i++) {
        f32x4 Av = A4[idx], pv = PREV4[idx], dtv = DTX4[idx];
#pragma unroll
        for (int j = 0; j < 4; j++) {
            v[j] = fmaf(Av[j], v[j], pv[j] * dtv[j]);
            x[j] = fmaf(dtv[j], v[j], x[j]);
        }
        PREV4[idx] = v;
        DTX4[idx] = x;
        idx += DDIM / 4;
    }
}

extern "C" void kernel_launch(void* const* d_in, const int* in_sizes, int n_in,
                              void* d_out, int out_size, void* d_ws, size_t ws_size,
                              hipStream_t stream) {
    const float* force = (const float*)d_in[2];
    const float* WA  = (const float*)d_in[5];
    const float* bA  = (const float*)d_in[6];
    const float* WB  = (const float*)d_in[7];
    const float* bB  = (const float*)d_in[8];
    const float* Wdt = (const float*)d_in[9];
    const float* bdt = (const float*)d_in[10];

    float* xseq = (float*)d_out;                          // [B,L,D] first output
    float* vseq = xseq + (size_t)MROWS * DDIM;            // [B,L,D] second output

    char* ws = (char*)d_ws;
    float*  wsA   = (float*) ws;                             // 64 MB: A gates (live to end)
    ushort* Fb    = (ushort*)(ws + ((size_t)64  << 20));     // 32 MB: bf16 force (dead after gemm)
    ushort* Wcat  = (ushort*)(ws + ((size_t)96  << 20));     //  6 MB: bf16 [WA;WB;Wdt]
    // summ/carry reuse the Fb region (only written after gemm completes):
    float4* summ  = (float4*)(ws + ((size_t)64  << 20));     //  8 MB: chunk summaries
    float2* carry = (float2*)(ws + ((size_t)72  << 20));     //  4 MB: chunk carries

    const int n4_force = MROWS * DDIM / 4;     // 4194304

    cvt4<<<n4_force / 256, 256, 0, stream>>>(force, Fb, n4_force);
    cvt4_w3<<<3 * N4W / 256, 256, 0, stream>>>(WA, WB, Wdt, Wcat);

    gemm_fused<<<dim3(128, 24), 256, 0, stream>>>(Fb, Wcat, bA, bB, bdt,
                                                  wsA, vseq, xseq);

    scan_pass1<<<BDIM * NCH, 256, 0, stream>>>(wsA, vseq, xseq, summ);
    scan_pass2<<<16, 256, 0, stream>>>(summ, carry);
    scan_pass3<<<BDIM * NCH, 256, 0, stream>>>(wsA, vseq, xseq, carry);
}

// Round 5
// 289.850 us; speedup vs baseline: 1.0673x; 1.0673x over previous
//
#include <hip/hip_runtime.h>
#include <hip/hip_bf16.h>
#include <math.h>

// ParallelMLayer: x_seq, v_seq = scan over A=sigmoid(F@WA.T+bA),
// dt=softplus(F@Wdt.T+bdt)*0.1*1.5^(d/128), B=(F@WB.T+bB)*dt
// v_t = A_t v_{t-1} + B_t ; x_t = x_{t-1} + dt_t * v_t
//
// R5: GEMM BK=64 with XOR-swizzled gload_lds (pre-swizzled global source +
// swizzled ds_read, rule #21) -> conflict-free LDS reads. Scans unchanged.

#define BDIM 4
#define LSEQ 4096
#define DDIM 1024
#define MROWS (BDIM*LSEQ)   // 16384
#define NCH 128             // scan chunks per sequence
#define CLEN (LSEQ/NCH)     // 32
#define N4W (DDIM*DDIM/4)   // 262144 (2^18)
#define BK 64

typedef __attribute__((ext_vector_type(8))) unsigned short u16x8;
typedef __attribute__((ext_vector_type(8))) short s16x8;
typedef __attribute__((ext_vector_type(4))) float f32x4;

__device__ inline ushort f2bf(float f) {
    unsigned u = __builtin_bit_cast(unsigned, f);
    unsigned r = (u + 0x7fffu + ((u >> 16) & 1u)) >> 16;
    return (ushort)r;
}

__device__ inline void gld_lds16(const ushort* g, ushort* l) {
    __builtin_amdgcn_global_load_lds(
        (const __attribute__((address_space(1))) void*)g,
        (__attribute__((address_space(3))) void*)l, 16, 0, 0);
}

// ---- f32 -> bf16 conversion, 4 elems/thread ----
__global__ void cvt4(const float* __restrict__ src, ushort* __restrict__ dst, int n4) {
    int i = blockIdx.x * 256 + threadIdx.x;
    if (i >= n4) return;
    float4 v = reinterpret_cast<const float4*>(src)[i];
    ushort4 o;
    o.x = f2bf(v.x); o.y = f2bf(v.y); o.z = f2bf(v.z); o.w = f2bf(v.w);
    reinterpret_cast<ushort4*>(dst)[i] = o;
}

// ---- three equal-size weight matrices -> one concatenated bf16 buffer ----
__global__ void cvt4_w3(const float* __restrict__ s0, const float* __restrict__ s1,
                        const float* __restrict__ s2, ushort* __restrict__ dst) {
    int i = blockIdx.x * 256 + threadIdx.x;      // 0 .. 3*N4W-1
    int w = i >> 18;                             // N4W = 2^18
    int j = i & (N4W - 1);
    const float* s = (w == 0) ? s0 : (w == 1) ? s1 : s2;
    float4 v = reinterpret_cast<const float4*>(s)[j];
    ushort4 o;
    o.x = f2bf(v.x); o.y = f2bf(v.y); o.z = f2bf(v.z); o.w = f2bf(v.w);
    reinterpret_cast<ushort4*>(dst)[i] = o;
}

// ---- fused GEMM: C[i][j] = sum_k F[i][k] * Wcat[j][k] ----
// 128x128 tile, BK=64. Staging: global_load_lds(16B), LDS linear [128][64],
// source pre-swizzled so physical chunk c of row R holds global chunk c^(R&7);
// ds_read applies the same XOR -> all 32 banks covered uniformly (conflict-free).
__global__ __launch_bounds__(256) void gemm_fused(
    const ushort* __restrict__ F, const ushort* __restrict__ Wc,
    const float* __restrict__ biasA, const float* __restrict__ biasB,
    const float* __restrict__ biasDt,
    float* __restrict__ outA, float* __restrict__ outPre, float* __restrict__ outDt)
{
    __shared__ ushort As[128 * BK];   // 16 KB
    __shared__ ushort Bs[128 * BK];   // 16 KB
    const int t = threadIdx.x;
    const int bi = blockIdx.x;   // 0..127 M tiles
    const int bj = blockIdx.y;   // 0..23  N tiles
    const int lane = t & 63, wid = t >> 6;
    const int wm = wid >> 1, wn = wid & 1;   // 2x2 waves, each 64x64 out
    const int lr = lane & 15, lg = lane >> 4;
    const int rr = lane >> 3;    // row-within-8 for staging
    const int cc = lane & 7;     // 16B chunk 0..7 for staging

    const size_t aBase = (size_t)bi * 128;
    const size_t bBase = (size_t)bj * 128;

    // staging: issue i covers rows i*32 + wid*8 .. +7; lane covers (rr, chunk cc)
    // source chunk is pre-swizzled: global chunk = cc ^ (R&7)
    const ushort* gA[4]; const ushort* gB[4];
    ushort* lA[4]; ushort* lB[4];
#pragma unroll
    for (int i = 0; i < 4; i++) {
        const int R = i * 32 + wid * 8 + rr;
        const int sw = (cc ^ (R & 7)) * 8;
        gA[i] = F  + (aBase + R) * DDIM + sw;
        gB[i] = Wc + (bBase + R) * DDIM + sw;
        lA[i] = As + (i * 32 + wid * 8) * BK;   // wave-uniform base; HW adds lane*16B
        lB[i] = Bs + (i * 32 + wid * 8) * BK;
    }

    f32x4 acc[4][4] = {};

    for (int k0 = 0; k0 < DDIM; k0 += BK) {
        __syncthreads();                 // prev iter's ds_reads done before overwrite
#pragma unroll
        for (int i = 0; i < 4; i++) gld_lds16(gA[i] + k0, lA[i]);
#pragma unroll
        for (int i = 0; i < 4; i++) gld_lds16(gB[i] + k0, lB[i]);
        __syncthreads();                 // drains vmcnt before barrier
#pragma unroll
        for (int kk = 0; kk < 2; kk++) {
            s16x8 af[4], bf[4];
#pragma unroll
            for (int m = 0; m < 4; m++) {
                const int r = wm * 64 + m * 16 + lr;
                const int p = (kk * 4 + lg) ^ (lr & 7);   // un-swizzle on read
                af[m] = *reinterpret_cast<const s16x8*>(&As[r * BK + p * 8]);
            }
#pragma unroll
            for (int n = 0; n < 4; n++) {
                const int r = wn * 64 + n * 16 + lr;
                const int p = (kk * 4 + lg) ^ (lr & 7);
                bf[n] = *reinterpret_cast<const s16x8*>(&Bs[r * BK + p * 8]);
            }
#pragma unroll
            for (int m = 0; m < 4; m++)
#pragma unroll
                for (int n = 0; n < 4; n++)
                    acc[m][n] = __builtin_amdgcn_mfma_f32_16x16x32_bf16(af[m], bf[n], acc[m][n], 0, 0, 0);
        }
    }

    // epilogue: C/D layout col=lane&15, row=(lane>>4)*4+reg
    const int mat = bj >> 3;                     // 0:A 1:B-pre 2:dt
    const int colBase = (bj & 7) * 128 + wn * 64;
    const size_t rowBase = (size_t)bi * 128 + wm * 64;

    if (mat == 0) {
#pragma unroll
        for (int n = 0; n < 4; n++) {
            const int d = colBase + n * 16 + lr;
            const float bb = biasA[d];
#pragma unroll
            for (int m = 0; m < 4; m++)
#pragma unroll
                for (int r = 0; r < 4; r++) {
                    const size_t row = rowBase + m * 16 + lg * 4 + r;
                    float s = acc[m][n][r] + bb;
                    outA[row * DDIM + d] = 1.0f / (1.0f + expf(-s));
                }
        }
    } else if (mat == 1) {
#pragma unroll
        for (int n = 0; n < 4; n++) {
            const int d = colBase + n * 16 + lr;
            const float bb = biasB[d];
#pragma unroll
            for (int m = 0; m < 4; m++)
#pragma unroll
                for (int r = 0; r < 4; r++) {
                    const size_t row = rowBase + m * 16 + lg * 4 + r;
                    outPre[row * DDIM + d] = acc[m][n][r] + bb;
                }
        }
    } else {
#pragma unroll
        for (int n = 0; n < 4; n++) {
            const int d = colBase + n * 16 + lr;
            const float bb = biasDt[d];
            const float scl = 0.1f * exp2f(0.58496250072f * (float)(d >> 7)); // 0.1*1.5^(d/128)
#pragma unroll
            for (int m = 0; m < 4; m++)
#pragma unroll
                for (int r = 0; r < 4; r++) {
                    const size_t row = rowBase + m * 16 + lg * 4 + r;
                    float s = acc[m][n][r] + bb;
                    float sp = fmaxf(s, 0.0f) + log1pf(expf(-fabsf(s)));
                    outDt[row * DDIM + d] = sp * scl;
                }
        }
    }
}

// ---- scan pass 1: per (b, chunk, d) composite map (a, c, bv, bx), float4 ----
__global__ void scan_pass1(const float* __restrict__ A, const float* __restrict__ PRE,
                           const float* __restrict__ DT, float4* __restrict__ summ)
{
    const int c = blockIdx.x & (NCH - 1);
    const int b = blockIdx.x >> 7;       // NCH = 128
    const int d4 = threadIdx.x;          // 0..255, covers d = 4*d4..+3
    const f32x4* A4   = (const f32x4*)A;
    const f32x4* PRE4 = (const f32x4*)PRE;
    const f32x4* DT4  = (const f32x4*)DT;
    size_t idx = ((size_t)b * LSEQ + (size_t)c * CLEN) * (DDIM / 4) + d4;
    f32x4 a = {1.f,1.f,1.f,1.f}, cc = {}, bv = {}, bx = {};
    for (int i = 0; i < CLEN; i++) {
        f32x4 Av = A4[idx], pv = PRE4[idx], dtv = DT4[idx];
#pragma unroll
        for (int j = 0; j < 4; j++) {
            a[j] *= Av[j];
            cc[j] = fmaf(dtv[j], a[j], cc[j]);
            bv[j] = fmaf(Av[j], bv[j], pv[j] * dtv[j]);
            bx[j] = fmaf(dtv[j], bv[j], bx[j]);
        }
        idx += DDIM / 4;
    }
    const size_t base = ((size_t)b * NCH + c) * DDIM + (size_t)d4 * 4;
#pragma unroll
    for (int j = 0; j < 4; j++)
        summ[base + j] = make_float4(a[j], cc[j], bv[j], bx[j]);
}

// ---- scan pass 2: serial over chunks per channel -> carry-in (v, x) ----
__global__ void scan_pass2(const float4* __restrict__ summ, float2* __restrict__ carry)
{
    const int idx = blockIdx.x * 256 + threadIdx.x;   // 4096 channels
    const int b = idx >> 10, d = idx & 1023;
    float v = 0.0f, x = 0.0f;
    for (int c = 0; c < NCH; c++) {
        const size_t o = ((size_t)b * NCH + c) * DDIM + d;
        carry[o] = make_float2(v, x);
        float4 s = summ[o];
        x = x + s.y * v + s.w;   // x' = x + c*v + bx (uses OLD v)
        v = s.x * v + s.z;       // v' = a*v + bv
    }
}

// ---- scan pass 3: finalize with carry; in-place pre->v_seq, dt->x_seq ----
__global__ void scan_pass3(const float* __restrict__ A, float* __restrict__ PREV,
                           float* __restrict__ DTX, const float2* __restrict__ carry)
{
    const int c = blockIdx.x & (NCH - 1);
    const int b = blockIdx.x >> 7;
    const int d4 = threadIdx.x;
    const f32x4* A4 = (const f32x4*)A;
    f32x4* PREV4 = (f32x4*)PREV;
    f32x4* DTX4  = (f32x4*)DTX;
    size_t idx = ((size_t)b * LSEQ + (size_t)c * CLEN) * (DDIM / 4) + d4;
    const size_t cbase = ((size_t)b * NCH + c) * DDIM + (size_t)d4 * 4;
    f32x4 v, x;
#pragma unroll
    for (int j = 0; j < 4; j++) {
        float2 cr = carry[cbase + j];
        v[j] = cr.x; x[j] = cr.y;
    }
    for (int i = 0; i < CLEN; i++) {
        f32x4 Av = A4[idx], pv = PREV4[idx], dtv = DTX4[idx];
#pragma unroll
        for (int j = 0; j < 4; j++) {
            v[j] = fmaf(Av[j], v[j], pv[j] * dtv[j]);
            x[j] = fmaf(dtv[j], v[j], x[j]);
        }
        PREV4[idx] = v;
        DTX4[idx] = x;
        idx += DDIM / 4;
    }
}

extern "C" void kernel_launch(void* const* d_in, const int* in_sizes, int n_in,
                              void* d_out, int out_size, void* d_ws, size_t ws_size,
                              hipStream_t stream) {
    const float* force = (const float*)d_in[2];
    const float* WA  = (const float*)d_in[5];
    const float* bA  = (const float*)d_in[6];
    const float* WB  = (const float*)d_in[7];
    const float* bB  = (const float*)d_in[8];
    const float* Wdt = (const float*)d_in[9];
    const float* bdt = (const float*)d_in[10];

    float* xseq = (float*)d_out;                          // [B,L,D] first output
    float* vseq = xseq + (size_t)MROWS * DDIM;            // [B,L,D] second output

    char* ws = (char*)d_ws;
    float*  wsA   = (float*) ws;                             // 64 MB: A gates (live to end)
    ushort* Fb    = (ushort*)(ws + ((size_t)64  << 20));     // 32 MB: bf16 force (dead after gemm)
    ushort* Wcat  = (ushort*)(ws + ((size_t)96  << 20));     //  6 MB: bf16 [WA;WB;Wdt]
    // summ/carry reuse the Fb region (only written after gemm completes):
    float4* summ  = (float4*)(ws + ((size_t)64  << 20));     //  8 MB: chunk summaries
    float2* carry = (float2*)(ws + ((size_t)72  << 20));     //  4 MB: chunk carries

    const int n4_force = MROWS * DDIM / 4;     // 4194304

    cvt4<<<n4_force / 256, 256, 0, stream>>>(force, Fb, n4_force);
    cvt4_w3<<<3 * N4W / 256, 256, 0, stream>>>(WA, WB, Wdt, Wcat);

    gemm_fused<<<dim3(128, 24), 256, 0, stream>>>(Fb, Wcat, bA, bB, bdt,
                                                  wsA, vseq, xseq);

    scan_pass1<<<BDIM * NCH, 256, 0, stream>>>(wsA, vseq, xseq, summ);
    scan_pass2<<<16, 256, 0, stream>>>(summ, carry);
    scan_pass3<<<BDIM * NCH, 256, 0, stream>>>(wsA, vseq, xseq, carry);
}